// Round 3
// baseline (42.161 us; speedup 1.0000x reference)
//
#include <hip/hip_runtime.h>
#include <math.h>

static constexpr int Bb   = 16;
static constexpr int Ww   = 256;
static constexpr int HWp  = 256 * 256;   // 65536
static constexpr int CF   = 128;
static constexpr int Kk   = 2;
static constexpr int SEGS = 16;
static constexpr int SEGLEN = HWp / SEGS;   // 4096 pixels per block
static constexpr int THREADS = 256;
static constexpr int NBLK = Bb * SEGS;      // 256 blocks

// Strict total order matching jax.lax.top_k: value descending, index ascending on ties.
__device__ __forceinline__ bool better(float v1, int i1, float v2, int i2) {
    return (v1 > v2) || ((v1 == v2) && (i1 < i2));
}

__device__ __forceinline__ void upd(float v, int p,
                                    float& v0, int& i0, float& v1, int& i1) {
    if (better(v, p, v0, i0)) { v1 = v0; i1 = i0; v0 = v; i0 = p; }
    else if (better(v, p, v1, i1)) { v1 = v; i1 = p; }
}

// merge sorted pair (b0,b1) into sorted pair (a0,a1)
__device__ __forceinline__ void merge2(float& a0, int& ia0, float& a1, int& ia1,
                                       float b0, int ib0, float b1, int ib1) {
    if (better(b0, ib0, a0, ia0)) {
        float na1; int nia1;
        if (better(a0, ia0, b1, ib1)) { na1 = a0; nia1 = ia0; }
        else                          { na1 = b1; nia1 = ib1; }
        a0 = b0; ia0 = ib0; a1 = na1; ia1 = nia1;
    } else if (better(b0, ib0, a1, ia1)) {
        a1 = b0; ia1 = ib0;
    }
}

// Single fused kernel.
// Phase A: one block per (batch, segment): one-pass dual-class partial top-2.
// Last finished block (device atomic) runs Phase B: merge + all gathers + writes.
__global__ __launch_bounds__(THREADS) void genpixel_fused(
    const float* __restrict__ infeat,
    const float* __restrict__ labelTpesudo,
    const float* __restrict__ labelT,
    const float* __restrict__ FeatureDA,
    float* __restrict__ ws_v, int* __restrict__ ws_i,
    unsigned int* __restrict__ counter,
    float* __restrict__ out)
{
    const int blk = blockIdx.x;         // 0..255
    const int b   = blk >> 4;           // 0..15
    const int seg = blk & 15;           // 0..15
    const int t   = threadIdx.x;

    // ---------------- Phase A ----------------
    {
        const float* x0p = infeat + ((size_t)b * 2 + 0) * HWp + seg * SEGLEN;
        const float* x1p = infeat + ((size_t)b * 2 + 1) * HWp + seg * SEGLEN;

        float u0 = -INFINITY, u1 = -INFINITY;  int ui0 = 0x7fffffff, ui1 = 0x7fffffff;
        float w0 = -INFINITY, w1 = -INFINITY;  int wi0 = 0x7fffffff, wi1 = 0x7fffffff;

        #pragma unroll
        for (int it = 0; it < SEGLEN / (THREADS * 4); ++it) {   // 4 iterations
            const int p = it * (THREADS * 4) + t * 4;
            const float4 a  = *(const float4*)(x0p + p);
            const float4 bb = *(const float4*)(x1p + p);
            const float ax[4] = {a.x, a.y, a.z, a.w};
            const float bx[4] = {bb.x, bb.y, bb.z, bb.w};
            #pragma unroll
            for (int e = 0; e < 4; ++e) {
                const float m  = fmaxf(ax[e], bx[e]);
                const float e0 = expf(ax[e] - m);
                const float e1 = expf(bx[e] - m);
                const float s  = e0 + e1;
                const float va = e0 / s;     // bit-exact vs reference formula
                const float vb = e1 / s;
                const int gp = seg * SEGLEN + p + e;
                upd(va, gp, u0, ui0, u1, ui1);
                upd(vb, gp, w0, wi0, w1, wi1);
            }
        }

        // 64-lane butterfly, in-register
        #pragma unroll
        for (int m = 1; m < 64; m <<= 1) {
            float ou0 = __shfl_xor(u0, m), ou1 = __shfl_xor(u1, m);
            int  oui0 = __shfl_xor(ui0, m), oui1 = __shfl_xor(ui1, m);
            float ow0 = __shfl_xor(w0, m), ow1 = __shfl_xor(w1, m);
            int  owi0 = __shfl_xor(wi0, m), owi1 = __shfl_xor(wi1, m);
            merge2(u0, ui0, u1, ui1, ou0, oui0, ou1, oui1);
            merge2(w0, wi0, w1, wi1, ow0, owi0, ow1, owi1);
        }

        __shared__ float sv[4][2][2];
        __shared__ int   si[4][2][2];
        const int wave = t >> 6;
        if ((t & 63) == 0) {
            sv[wave][0][0] = u0; sv[wave][0][1] = u1;
            sv[wave][1][0] = w0; sv[wave][1][1] = w1;
            si[wave][0][0] = ui0; si[wave][0][1] = ui1;
            si[wave][1][0] = wi0; si[wave][1][1] = wi1;
        }
        __syncthreads();
        if (t == 0) {
            #pragma unroll
            for (int wv = 1; wv < 4; ++wv) {
                merge2(sv[0][0][0], si[0][0][0], sv[0][0][1], si[0][0][1],
                       sv[wv][0][0], si[wv][0][0], sv[wv][0][1], si[wv][0][1]);
                merge2(sv[0][1][0], si[0][1][0], sv[0][1][1], si[0][1][1],
                       sv[wv][1][0], si[wv][1][0], sv[wv][1][1], si[wv][1][1]);
            }
            const int base = ((b * SEGS + seg) * 2) * 2;  // [b][seg][cls][entry]
            ws_v[base + 0] = sv[0][0][0]; ws_v[base + 1] = sv[0][0][1];
            ws_v[base + 2] = sv[0][1][0]; ws_v[base + 3] = sv[0][1][1];
            ws_i[base + 0] = si[0][0][0]; ws_i[base + 1] = si[0][0][1];
            ws_i[base + 2] = si[0][1][0]; ws_i[base + 3] = si[0][1][1];
        }
    }

    // ---------------- last-block handoff ----------------
    __shared__ int s_last;
    if (t == 0) {
        __threadfence();                       // release ws writes (device scope)
        const unsigned int old = atomicAdd(counter, 1u);
        s_last = (old == NBLK - 1) ? 1 : 0;
    }
    __syncthreads();
    if (!s_last) return;
    __threadfence();                           // acquire: see all blocks' ws writes

    // ---------------- Phase B (single block, 256 threads) ----------------
    __shared__ int   p_idx[64];
    __shared__ float p_val[64];
    if (t < 64) {
        const int pi = t;                       // point id, class-major
        const int c  = pi / (Bb * Kk);
        const int pb = (pi / Kk) % Bb;
        const int j  = pi % Kk;
        float bv0 = -INFINITY, bv1 = -INFINITY;
        int   bi0 = 0x7fffffff, bi1 = 0x7fffffff;
        for (int s2 = 0; s2 < SEGS; ++s2) {
            const int base = ((pb * SEGS + s2) * 2 + c) * 2;
            #pragma unroll
            for (int e = 0; e < 2; ++e) {
                const float v = ws_v[base + e];
                const int   i = ws_i[base + e];
                if (better(v, i, bv0, bi0)) { bv1 = bv0; bi1 = bi0; bv0 = v; bi0 = i; }
                else if (better(v, i, bv1, bi1)) { bv1 = v; bi1 = i; }
            }
        }
        p_idx[pi] = (j == 0) ? bi0 : bi1;
        p_val[pi] = (j == 0) ? bv0 : bv1;
    }
    __syncthreads();

    // Feature gathers: 64 points x 128 channels, 32 independent loads/thread.
    // Output layout (flat float32, 8768 elems):
    //   [0,128) classiferT (64,2) | [128,8320) patchFeatDA (64,128)
    //   [8320,8384) labelTTrue | [8384,8448) labelpesudo | [8448,8512) provalue
    //   [8512,8768) pointXY (64,2,2) = [px, min(px+31,255), py, min(py+31,255)]
    #pragma unroll
    for (int q = 0; q < (64 * CF) / THREADS; ++q) {
        const int g  = q * THREADS + t;
        const int pi = g >> 7;               // g / 128
        const int ch = g & 127;              // g % 128
        const int pb = (pi / Kk) % Bb;
        const int idx = p_idx[pi];
        out[128 + pi * CF + ch] = FeatureDA[((size_t)pb * CF + ch) * HWp + idx];
    }
    if (t < 64) {
        const int pi = t;
        const int pb = (pi / Kk) % Bb;
        const int idx = p_idx[pi];
        const int py = idx >> 8;
        const int px = idx & (Ww - 1);
        out[pi * 2 + 0] = infeat[((size_t)pb * 2 + 0) * HWp + idx];
        out[pi * 2 + 1] = infeat[((size_t)pb * 2 + 1) * HWp + idx];
        out[8320 + pi] = labelT[(size_t)pb * HWp + idx];
        out[8384 + pi] = labelTpesudo[(size_t)pb * HWp + idx];
        out[8448 + pi] = p_val[pi];
        out[8512 + pi * 4 + 0] = (float)px;
        out[8512 + pi * 4 + 1] = (float)min(px + 31, 255);
        out[8512 + pi * 4 + 2] = (float)py;
        out[8512 + pi * 4 + 3] = (float)min(py + 31, 255);
    }
}

extern "C" void kernel_launch(void* const* d_in, const int* in_sizes, int n_in,
                              void* d_out, int out_size, void* d_ws, size_t ws_size,
                              hipStream_t stream) {
    const float* infeat       = (const float*)d_in[0];
    const float* labelTpesudo = (const float*)d_in[1];
    const float* labelT       = (const float*)d_in[2];
    const float* FeatureDA    = (const float*)d_in[3];
    float* out = (float*)d_out;

    // ws layout: ws_v (16*16*4 f32 = 4 KB) | ws_i (4 KB) | counter (4 B)
    float*        ws_v    = (float*)d_ws;
    int*          ws_i    = (int*)((char*)d_ws + Bb * SEGS * 4 * sizeof(float));
    unsigned int* counter = (unsigned int*)((char*)d_ws + 2 * Bb * SEGS * 4 * sizeof(float));

    hipMemsetAsync(counter, 0, sizeof(unsigned int), stream);  // graph-capturable node
    genpixel_fused<<<NBLK, THREADS, 0, stream>>>(
        infeat, labelTpesudo, labelT, FeatureDA, ws_v, ws_i, counter, out);
}